// Round 8
// baseline (215.752 us; speedup 1.0000x reference)
//
#include <hip/hip_runtime.h>
#include <hip/hip_bf16.h>

typedef __bf16 bf16;
typedef __bf16 bf16x4 __attribute__((ext_vector_type(4)));
typedef __bf16 bf16x8 __attribute__((ext_vector_type(8)));
typedef short  s16x4  __attribute__((ext_vector_type(4)));
typedef float  f32x4  __attribute__((ext_vector_type(4)));

// 0.125 (1/sqrt(64)) * log2(e): folded into Q at projection time -> base-2 softmax
#define QSCALE 0.18033688011112042f

// async 16B global -> LDS; dest = wave-uniform base + lane*16 (m97 contract)
__device__ __forceinline__ void load16_lds(const bf16* g, bf16* l) {
    __builtin_amdgcn_global_load_lds(
        (const __attribute__((address_space(1))) unsigned int*)g,
        (__attribute__((address_space(3))) unsigned int*)l, 16, 0, 0);
}

// ---------------------------------------------------------------------------
// fp32 -> bf16 conversion. Grid: (2048, 5). blockIdx.y selects tensor.
// ---------------------------------------------------------------------------
__global__ void cvt_f32_bf16(
    const float* __restrict__ s0, const float* __restrict__ s1,
    const float* __restrict__ s2, const float* __restrict__ s3,
    const float* __restrict__ s4,
    bf16* __restrict__ d0, bf16* __restrict__ d1, bf16* __restrict__ d2,
    bf16* __restrict__ d3, bf16* __restrict__ d4)
{
    const float* s; bf16* d; int nblk;
    switch (blockIdx.y) {
        case 0:  s = s0; d = d0; nblk = 2048; break;
        case 1:  s = s1; d = d1; nblk = 512;  break;
        case 2:  s = s2; d = d2; nblk = 512;  break;
        case 3:  s = s3; d = d3; nblk = 512;  break;
        default: s = s4; d = d4; nblk = 512;  break;
    }
    if ((int)blockIdx.x >= nblk) return;
    int idx = blockIdx.x * 256 + threadIdx.x;
    float4 a = ((const float4*)s)[idx * 2];
    float4 b = ((const float4*)s)[idx * 2 + 1];
    bf16x8 o;
    o[0] = (bf16)a.x; o[1] = (bf16)a.y; o[2] = (bf16)a.z; o[3] = (bf16)a.w;
    o[4] = (bf16)b.x; o[5] = (bf16)b.y; o[6] = (bf16)b.z; o[7] = (bf16)b.w;
    *(bf16x8*)&d[idx * 8] = o;
}

// ---------------------------------------------------------------------------
// Fused Q/K/V projection. Grid: (24, 32) = 768 blocks -> 3 blocks/CU.
// ---------------------------------------------------------------------------
__global__ __launch_bounds__(256, 2) void qkv_gemm(
    const bf16* __restrict__ A,
    const bf16* __restrict__ Wq, const bf16* __restrict__ Wk,
    const bf16* __restrict__ Wv,
    bf16* __restrict__ qbuf, bf16* __restrict__ kbuf, bf16* __restrict__ vT)
{
    __shared__ bf16 sA[128 * 32];
    __shared__ bf16 sB[128 * 32];

    const int which = blockIdx.x >> 3;          // 0=Q 1=K 2=V
    const int n0    = (blockIdx.x & 7) * 128;
    const int m0    = blockIdx.y * 128;
    const bf16* B   = (which == 0) ? Wq : (which == 1) ? Wk : Wv;

    const int tid  = threadIdx.x;
    const int lane = tid & 63;
    const int w    = tid >> 6;
    const int wr   = w >> 1, wc = w & 1;
    const int r    = lane & 15;
    const int qd   = lane >> 4;

    f32x4 acc[4][4];
    const f32x4 zero4 = {0.f, 0.f, 0.f, 0.f};
#pragma unroll
    for (int mi = 0; mi < 4; ++mi)
#pragma unroll
        for (int ni = 0; ni < 4; ++ni) acc[mi][ni] = zero4;

    for (int kt = 0; kt < 32; ++kt) {
        const bf16* gA = A + (size_t)m0 * 1024 + kt * 32;
        const bf16* gB = B + (size_t)n0 * 1024 + kt * 32;
        __syncthreads();
#pragma unroll
        for (int j = 0; j < 2; ++j) {
            int task = j * 256 + tid;
            int row  = task >> 2, ch = task & 3;
            int ldsb = (j * 256 + w * 64) * 8;
            load16_lds(gA + (size_t)row * 1024 + ch * 8, &sA[ldsb]);
            load16_lds(gB + (size_t)row * 1024 + ch * 8, &sB[ldsb]);
        }
        __syncthreads();

        bf16x8 af[4], bfr[4];
#pragma unroll
        for (int mi = 0; mi < 4; ++mi)
            af[mi] = *(const bf16x8*)&sA[(wr * 64 + mi * 16 + r) * 32 + qd * 8];
#pragma unroll
        for (int ni = 0; ni < 4; ++ni)
            bfr[ni] = *(const bf16x8*)&sB[(wc * 64 + ni * 16 + r) * 32 + qd * 8];
#pragma unroll
        for (int mi = 0; mi < 4; ++mi)
#pragma unroll
            for (int ni = 0; ni < 4; ++ni)
                acc[mi][ni] = __builtin_amdgcn_mfma_f32_16x16x32_bf16(
                    af[mi], bfr[ni], acc[mi][ni], 0, 0, 0);
    }

    const float scale = (which == 0) ? QSCALE : 1.0f;
#pragma unroll
    for (int mi = 0; mi < 4; ++mi)
#pragma unroll
        for (int ni = 0; ni < 4; ++ni)
#pragma unroll
            for (int i = 0; i < 4; ++i) {
                int row = m0 + wr * 64 + mi * 16 + qd * 4 + i;
                int col = n0 + wc * 64 + ni * 16 + r;
                float v = acc[mi][ni][i] * scale;
                if (which == 0) {
                    qbuf[(size_t)row * 1024 + col] = (bf16)v;
                } else if (which == 1) {
                    kbuf[(size_t)row * 1024 + col] = (bf16)v;
                } else {
                    // vT[(b*16+h)*64 + p][s]; b=row>>11, s=row&2047, col=h*64+p
                    vT[((size_t)((row >> 11) * 1024 + col)) * 2048 + (row & 2047)] = (bf16)v;
                }
            }
}

// ---------------------------------------------------------------------------
// Output projection: out[4096,1024] = concat @ Wo^T + bo, fp32 out.
// 128x64 tile -> grid (16, 32) = 512 blocks.
// ---------------------------------------------------------------------------
__global__ __launch_bounds__(256, 2) void out_gemm(
    const bf16* __restrict__ A, const bf16* __restrict__ B,
    float* __restrict__ C, const float* __restrict__ bias)
{
    __shared__ bf16 sA[128 * 32];
    __shared__ bf16 sB[64 * 32];

    const int tid  = threadIdx.x;
    const int lane = tid & 63;
    const int w    = tid >> 6;
    const int wr   = w >> 1, wc = w & 1;
    const int r    = lane & 15;
    const int qd   = lane >> 4;
    const int m0   = blockIdx.y * 128;
    const int n0   = blockIdx.x * 64;

    f32x4 acc[4][2];
    const f32x4 zero4 = {0.f, 0.f, 0.f, 0.f};
#pragma unroll
    for (int mi = 0; mi < 4; ++mi)
#pragma unroll
        for (int ni = 0; ni < 2; ++ni) acc[mi][ni] = zero4;

    for (int kt = 0; kt < 32; ++kt) {
        const bf16* gA = A + (size_t)m0 * 1024 + kt * 32;
        const bf16* gB = B + (size_t)n0 * 1024 + kt * 32;
        __syncthreads();
#pragma unroll
        for (int j = 0; j < 2; ++j) {
            int task = j * 256 + tid;
            int row  = task >> 2, ch = task & 3;
            int ldsb = (j * 256 + w * 64) * 8;
            load16_lds(gA + (size_t)row * 1024 + ch * 8, &sA[ldsb]);
        }
        {
            int row = tid >> 2, ch = tid & 3;
            int ldsb = (w * 64) * 8;
            load16_lds(gB + (size_t)row * 1024 + ch * 8, &sB[ldsb]);
        }
        __syncthreads();

        bf16x8 af[4], bfr[2];
#pragma unroll
        for (int mi = 0; mi < 4; ++mi)
            af[mi] = *(const bf16x8*)&sA[(wr * 64 + mi * 16 + r) * 32 + qd * 8];
#pragma unroll
        for (int ni = 0; ni < 2; ++ni)
            bfr[ni] = *(const bf16x8*)&sB[(wc * 32 + ni * 16 + r) * 32 + qd * 8];
#pragma unroll
        for (int mi = 0; mi < 4; ++mi)
#pragma unroll
            for (int ni = 0; ni < 2; ++ni)
                acc[mi][ni] = __builtin_amdgcn_mfma_f32_16x16x32_bf16(
                    af[mi], bfr[ni], acc[mi][ni], 0, 0, 0);
    }

#pragma unroll
    for (int mi = 0; mi < 4; ++mi)
#pragma unroll
        for (int ni = 0; ni < 2; ++ni)
#pragma unroll
            for (int i = 0; i < 4; ++i) {
                int row = m0 + wr * 64 + mi * 16 + qd * 4 + i;
                int col = n0 + wc * 32 + ni * 16 + r;
                C[(size_t)row * 1024 + col] = acc[mi][ni][i] + bias[col];
            }
}

// ---------------------------------------------------------------------------
// Fused flash attention, chained-MFMA (no P LDS round-trip).
// Grid: (16, 32) = 512 blocks, 256 threads (4 waves), 128 q-rows/block.
// S^T = mfma(A=K, B=Q) -> C-layout of S^T IS the B-frag layout of the K=16
// MFMA, so P^T feeds PV directly from registers after exp2+pack.
// PV: O^T = V^T * P^T via v_mfma_f32_16x16x16bf16 (1k); V^T A-frags are
// natural b64 reads from the p-major sV tile. Row-sum l via all-ones A-frag.
// LDS: sK 64x72 + sV 64x72 = 18 KB, reused as 128x64 transpose scratch.
// ---------------------------------------------------------------------------
__global__ __launch_bounds__(256, 2) void attn_kernel(
    const bf16* __restrict__ qbuf, const bf16* __restrict__ kbuf,
    const bf16* __restrict__ vT, bf16* __restrict__ concat)
{
    __shared__ bf16 smem[2 * 64 * 72];          // sK | sV ; epilogue scratch
    bf16* sK = smem;
    bf16* sV = smem + 64 * 72;

    const int tid  = threadIdx.x;
    const int lane = tid & 63;
    const int w    = tid >> 6;
    const int r    = lane & 15;
    const int qd   = lane >> 4;
    const int qt   = blockIdx.x;        // 0..15
    const int bh   = blockIdx.y;        // 0..31
    const int b    = bh >> 4, h = bh & 15;
    const int qrow0 = b * 2048 + qt * 128;
    const size_t vbase = (size_t)bh * 64 * 2048;

    // all-ones A-frag for the row-sum MFMA (bf16 1.0 = 0x3F80)
    const s16x4 ones4 = {(short)0x3F80, (short)0x3F80, (short)0x3F80, (short)0x3F80};

    // Q fragments in registers: rows w*32+mi*16+r, cols ks*32+qd*8 (pre-scaled)
    bf16x8 aq[2][2];
#pragma unroll
    for (int mi = 0; mi < 2; ++mi)
#pragma unroll
        for (int ks = 0; ks < 2; ++ks)
            aq[mi][ks] = *(const bf16x8*)&qbuf[
                (size_t)(qrow0 + w * 32 + mi * 16 + r) * 1024 + h * 64 + ks * 32 + qd * 8];

    f32x4 acc_o[2][4], acc_l[2];        // O^T tiles [mi][pj]; l per mi
    const f32x4 zero4 = {0.f, 0.f, 0.f, 0.f};
#pragma unroll
    for (int mi = 0; mi < 2; ++mi) {
        acc_l[mi] = zero4;
#pragma unroll
        for (int pj = 0; pj < 4; ++pj) acc_o[mi][pj] = zero4;
    }

    for (int tt = 0; tt < 32; ++tt) {
        // global loads to registers first (in flight across the barrier)
        bf16x8 rk[2], rv[2];
        int krow[2], kch[2];
#pragma unroll
        for (int t = 0; t < 2; ++t) {
            int flat = t * 256 + tid;        // 0..511
            krow[t] = flat >> 3; kch[t] = flat & 7;
            rk[t] = *(const bf16x8*)&kbuf[(size_t)(b * 2048 + tt * 64 + krow[t]) * 1024 + h * 64 + kch[t] * 8];
            rv[t] = *(const bf16x8*)&vT[vbase + (size_t)krow[t] * 2048 + tt * 64 + kch[t] * 8];
        }
        __syncthreads();   // prev iteration's sK/sV reads complete
#pragma unroll
        for (int t = 0; t < 2; ++t) {
            *(bf16x8*)&sK[krow[t] * 72 + kch[t] * 8] = rk[t];
            *(bf16x8*)&sV[krow[t] * 72 + kch[t] * 8] = rv[t];
        }
        __syncthreads();

        // S^T = K Q^T : A = K-frag (lane&15 = key t), B = Q-frag (lane&15 = q)
        // D[t][q]: col = lane&15 = q, row t = qd*4 + i
        f32x4 accs[2][4];
#pragma unroll
        for (int mi = 0; mi < 2; ++mi)
#pragma unroll
            for (int ni = 0; ni < 4; ++ni) accs[mi][ni] = zero4;
#pragma unroll
        for (int ks = 0; ks < 2; ++ks)
#pragma unroll
            for (int ni = 0; ni < 4; ++ni) {
                bf16x8 ak = *(const bf16x8*)&sK[(ni * 16 + r) * 72 + ks * 32 + qd * 8];
#pragma unroll
                for (int mi = 0; mi < 2; ++mi)
                    accs[mi][ni] = __builtin_amdgcn_mfma_f32_16x16x32_bf16(
                        ak, aq[mi][ks], accs[mi][ni], 0, 0, 0);
            }

        // P^T = exp2(S^T), packed bf16 -> directly the B-frag of the K=16 MFMA
        s16x4 pfrag[2][4];
#pragma unroll
        for (int mi = 0; mi < 2; ++mi)
#pragma unroll
            for (int ni = 0; ni < 4; ++ni) {
                bf16x4 pv;
#pragma unroll
                for (int i = 0; i < 4; ++i) pv[i] = (bf16)exp2f(accs[mi][ni][i]);
                pfrag[mi][ni] = __builtin_bit_cast(s16x4, pv);
            }

        // O^T += V^T P^T ; l += 1^T P^T   (K=16 MFMAs, k = t within ni-tile)
#pragma unroll
        for (int ni = 0; ni < 4; ++ni) {
#pragma unroll
            for (int pj = 0; pj < 4; ++pj) {
                bf16x4 av = *(const bf16x4*)&sV[(pj * 16 + r) * 72 + ni * 16 + qd * 4];
                s16x4  avs = __builtin_bit_cast(s16x4, av);
#pragma unroll
                for (int mi = 0; mi < 2; ++mi)
                    acc_o[mi][pj] = __builtin_amdgcn_mfma_f32_16x16x16bf16_1k(
                        avs, pfrag[mi][ni], acc_o[mi][pj], 0, 0, 0);
            }
#pragma unroll
            for (int mi = 0; mi < 2; ++mi)
                acc_l[mi] = __builtin_amdgcn_mfma_f32_16x16x16bf16_1k(
                    ones4, pfrag[mi][ni], acc_l[mi], 0, 0, 0);
        }
    }

    // epilogue: O^T -> O via LDS scratch (once), then coalesced b128 stores.
    // acc_l rows are all identical (ones A) -> l for column q is acc_l[mi][0].
    __syncthreads();                     // everyone done reading sK/sV
    bf16* scratch = smem;                // 128 x 64, stride 64 (16 KB)
#pragma unroll
    for (int mi = 0; mi < 2; ++mi) {
        float inv = 1.0f / acc_l[mi][0];
        int qloc  = w * 32 + mi * 16 + r;
#pragma unroll
        for (int pj = 0; pj < 4; ++pj)
#pragma unroll
            for (int i = 0; i < 4; ++i)
                scratch[qloc * 64 + pj * 16 + qd * 4 + i] =
                    (bf16)(acc_o[mi][pj][i] * inv);
    }
    __syncthreads();
    {
        int row  = tid >> 1;             // 0..127
        int half = tid & 1;              // 32-elem half-row
#pragma unroll
        for (int c = 0; c < 4; ++c) {
            bf16x8 v = *(const bf16x8*)&scratch[row * 64 + half * 32 + c * 8];
            *(bf16x8*)&concat[(size_t)(qrow0 + row) * 1024 + h * 64 + half * 32 + c * 8] = v;
        }
    }
}

// ---------------------------------------------------------------------------
extern "C" void kernel_launch(void* const* d_in, const int* in_sizes, int n_in,
                              void* d_out, int out_size, void* d_ws, size_t ws_size,
                              hipStream_t stream)
{
    const float* x  = (const float*)d_in[0];   // [4096, 1024]
    const float* Wq = (const float*)d_in[1];
    const float* Wk = (const float*)d_in[2];
    const float* Wv = (const float*)d_in[3];
    const float* Wo = (const float*)d_in[4];
    const float* bo = (const float*)d_in[5];
    float* out = (float*)d_out;

    char* ws = (char*)d_ws;
    bf16* xb     = (bf16*)(ws);
    bf16* Wqb    = (bf16*)(ws + (8u  << 20));
    bf16* Wkb    = (bf16*)(ws + (10u << 20));
    bf16* Wvb    = (bf16*)(ws + (12u << 20));
    bf16* Wob    = (bf16*)(ws + (14u << 20));
    bf16* qbuf   = (bf16*)(ws + (16u << 20)); // pre-scaled by QSCALE
    bf16* kbuf   = (bf16*)(ws + (24u << 20));
    bf16* vT     = (bf16*)(ws + (32u << 20)); // [32][64][2048]
    bf16* concat = (bf16*)(ws + (40u << 20));

    hipLaunchKernelGGL(cvt_f32_bf16, dim3(2048, 5), dim3(256), 0, stream,
                       x, Wq, Wk, Wv, Wo, xb, Wqb, Wkb, Wvb, Wob);
    hipLaunchKernelGGL(qkv_gemm, dim3(24, 32), dim3(256), 0, stream,
                       xb, Wqb, Wkb, Wvb, qbuf, kbuf, vT);
    hipLaunchKernelGGL(attn_kernel, dim3(16, 32), dim3(256), 0, stream,
                       qbuf, kbuf, vT, concat);
    hipLaunchKernelGGL(out_gemm, dim3(16, 32), dim3(256), 0, stream,
                       concat, Wob, out, bo);
}

// Round 9
// 204.959 us; speedup vs baseline: 1.0527x; 1.0527x over previous
//
#include <hip/hip_runtime.h>
#include <hip/hip_bf16.h>

typedef __bf16 bf16;
typedef __bf16 bf16x4 __attribute__((ext_vector_type(4)));
typedef __bf16 bf16x8 __attribute__((ext_vector_type(8)));
typedef short  s16x4  __attribute__((ext_vector_type(4)));
typedef float  f32x4  __attribute__((ext_vector_type(4)));

// 0.125 (1/sqrt(64)) * log2(e): folded into Q at projection time -> base-2 softmax
#define QSCALE 0.18033688011112042f

// async 16B global -> LDS; dest = wave-uniform base + lane*16 (m97 contract)
__device__ __forceinline__ void load16_lds(const bf16* g, bf16* l) {
    __builtin_amdgcn_global_load_lds(
        (const __attribute__((address_space(1))) unsigned int*)g,
        (__attribute__((address_space(3))) unsigned int*)l, 16, 0, 0);
}

// ---------------------------------------------------------------------------
// fp32 -> bf16 conversion. Grid: (2048, 5). blockIdx.y selects tensor.
// ---------------------------------------------------------------------------
__global__ void cvt_f32_bf16(
    const float* __restrict__ s0, const float* __restrict__ s1,
    const float* __restrict__ s2, const float* __restrict__ s3,
    const float* __restrict__ s4,
    bf16* __restrict__ d0, bf16* __restrict__ d1, bf16* __restrict__ d2,
    bf16* __restrict__ d3, bf16* __restrict__ d4)
{
    const float* s; bf16* d; int nblk;
    switch (blockIdx.y) {
        case 0:  s = s0; d = d0; nblk = 2048; break;
        case 1:  s = s1; d = d1; nblk = 512;  break;
        case 2:  s = s2; d = d2; nblk = 512;  break;
        case 3:  s = s3; d = d3; nblk = 512;  break;
        default: s = s4; d = d4; nblk = 512;  break;
    }
    if ((int)blockIdx.x >= nblk) return;
    int idx = blockIdx.x * 256 + threadIdx.x;
    float4 a = ((const float4*)s)[idx * 2];
    float4 b = ((const float4*)s)[idx * 2 + 1];
    bf16x8 o;
    o[0] = (bf16)a.x; o[1] = (bf16)a.y; o[2] = (bf16)a.z; o[3] = (bf16)a.w;
    o[4] = (bf16)b.x; o[5] = (bf16)b.y; o[6] = (bf16)b.z; o[7] = (bf16)b.w;
    *(bf16x8*)&d[idx * 8] = o;
}

// ---------------------------------------------------------------------------
// Fused Q/K/V projection. Grid: (24, 32) = 768 blocks -> 3 blocks/CU.
// ---------------------------------------------------------------------------
__global__ __launch_bounds__(256, 2) void qkv_gemm(
    const bf16* __restrict__ A,
    const bf16* __restrict__ Wq, const bf16* __restrict__ Wk,
    const bf16* __restrict__ Wv,
    bf16* __restrict__ qbuf, bf16* __restrict__ kbuf, bf16* __restrict__ vT)
{
    __shared__ bf16 sA[128 * 32];
    __shared__ bf16 sB[128 * 32];

    const int which = blockIdx.x >> 3;          // 0=Q 1=K 2=V
    const int n0    = (blockIdx.x & 7) * 128;
    const int m0    = blockIdx.y * 128;
    const bf16* B   = (which == 0) ? Wq : (which == 1) ? Wk : Wv;

    const int tid  = threadIdx.x;
    const int lane = tid & 63;
    const int w    = tid >> 6;
    const int wr   = w >> 1, wc = w & 1;
    const int r    = lane & 15;
    const int qd   = lane >> 4;

    f32x4 acc[4][4];
    const f32x4 zero4 = {0.f, 0.f, 0.f, 0.f};
#pragma unroll
    for (int mi = 0; mi < 4; ++mi)
#pragma unroll
        for (int ni = 0; ni < 4; ++ni) acc[mi][ni] = zero4;

    for (int kt = 0; kt < 32; ++kt) {
        const bf16* gA = A + (size_t)m0 * 1024 + kt * 32;
        const bf16* gB = B + (size_t)n0 * 1024 + kt * 32;
        __syncthreads();
#pragma unroll
        for (int j = 0; j < 2; ++j) {
            int task = j * 256 + tid;
            int row  = task >> 2, ch = task & 3;
            int ldsb = (j * 256 + w * 64) * 8;
            load16_lds(gA + (size_t)row * 1024 + ch * 8, &sA[ldsb]);
            load16_lds(gB + (size_t)row * 1024 + ch * 8, &sB[ldsb]);
        }
        __syncthreads();

        bf16x8 af[4], bfr[4];
#pragma unroll
        for (int mi = 0; mi < 4; ++mi)
            af[mi] = *(const bf16x8*)&sA[(wr * 64 + mi * 16 + r) * 32 + qd * 8];
#pragma unroll
        for (int ni = 0; ni < 4; ++ni)
            bfr[ni] = *(const bf16x8*)&sB[(wc * 64 + ni * 16 + r) * 32 + qd * 8];
#pragma unroll
        for (int mi = 0; mi < 4; ++mi)
#pragma unroll
            for (int ni = 0; ni < 4; ++ni)
                acc[mi][ni] = __builtin_amdgcn_mfma_f32_16x16x32_bf16(
                    af[mi], bfr[ni], acc[mi][ni], 0, 0, 0);
    }

    const float scale = (which == 0) ? QSCALE : 1.0f;
#pragma unroll
    for (int mi = 0; mi < 4; ++mi)
#pragma unroll
        for (int ni = 0; ni < 4; ++ni)
#pragma unroll
            for (int i = 0; i < 4; ++i) {
                int row = m0 + wr * 64 + mi * 16 + qd * 4 + i;
                int col = n0 + wc * 64 + ni * 16 + r;
                float v = acc[mi][ni][i] * scale;
                if (which == 0) {
                    qbuf[(size_t)row * 1024 + col] = (bf16)v;
                } else if (which == 1) {
                    kbuf[(size_t)row * 1024 + col] = (bf16)v;
                } else {
                    // vT[(b*16+h)*64 + p][s]; b=row>>11, s=row&2047, col=h*64+p
                    vT[((size_t)((row >> 11) * 1024 + col)) * 2048 + (row & 2047)] = (bf16)v;
                }
            }
}

// ---------------------------------------------------------------------------
// Output projection: out[4096,1024] = concat @ Wo^T + bo, fp32 out.
// 128x64 tile -> grid (16, 32) = 512 blocks.
// ---------------------------------------------------------------------------
__global__ __launch_bounds__(256, 2) void out_gemm(
    const bf16* __restrict__ A, const bf16* __restrict__ B,
    float* __restrict__ C, const float* __restrict__ bias)
{
    __shared__ bf16 sA[128 * 32];
    __shared__ bf16 sB[64 * 32];

    const int tid  = threadIdx.x;
    const int lane = tid & 63;
    const int w    = tid >> 6;
    const int wr   = w >> 1, wc = w & 1;
    const int r    = lane & 15;
    const int qd   = lane >> 4;
    const int m0   = blockIdx.y * 128;
    const int n0   = blockIdx.x * 64;

    f32x4 acc[4][2];
    const f32x4 zero4 = {0.f, 0.f, 0.f, 0.f};
#pragma unroll
    for (int mi = 0; mi < 4; ++mi)
#pragma unroll
        for (int ni = 0; ni < 2; ++ni) acc[mi][ni] = zero4;

    for (int kt = 0; kt < 32; ++kt) {
        const bf16* gA = A + (size_t)m0 * 1024 + kt * 32;
        const bf16* gB = B + (size_t)n0 * 1024 + kt * 32;
        __syncthreads();
#pragma unroll
        for (int j = 0; j < 2; ++j) {
            int task = j * 256 + tid;
            int row  = task >> 2, ch = task & 3;
            int ldsb = (j * 256 + w * 64) * 8;
            load16_lds(gA + (size_t)row * 1024 + ch * 8, &sA[ldsb]);
        }
        {
            int row = tid >> 2, ch = tid & 3;
            int ldsb = (w * 64) * 8;
            load16_lds(gB + (size_t)row * 1024 + ch * 8, &sB[ldsb]);
        }
        __syncthreads();

        bf16x8 af[4], bfr[2];
#pragma unroll
        for (int mi = 0; mi < 4; ++mi)
            af[mi] = *(const bf16x8*)&sA[(wr * 64 + mi * 16 + r) * 32 + qd * 8];
#pragma unroll
        for (int ni = 0; ni < 2; ++ni)
            bfr[ni] = *(const bf16x8*)&sB[(wc * 32 + ni * 16 + r) * 32 + qd * 8];
#pragma unroll
        for (int mi = 0; mi < 4; ++mi)
#pragma unroll
            for (int ni = 0; ni < 2; ++ni)
                acc[mi][ni] = __builtin_amdgcn_mfma_f32_16x16x32_bf16(
                    af[mi], bfr[ni], acc[mi][ni], 0, 0, 0);
    }

#pragma unroll
    for (int mi = 0; mi < 4; ++mi)
#pragma unroll
        for (int ni = 0; ni < 2; ++ni)
#pragma unroll
            for (int i = 0; i < 4; ++i) {
                int row = m0 + wr * 64 + mi * 16 + qd * 4 + i;
                int col = n0 + wc * 32 + ni * 16 + r;
                C[(size_t)row * 1024 + col] = acc[mi][ni][i] + bias[col];
            }
}

// ---------------------------------------------------------------------------
// Fused flash attention, chained-MFMA + single-barrier double-buffered K/V.
// Grid: (16, 32) = 512 blocks, 256 threads (4 waves), 128 q-rows/block.
// Per iter: store regs(tile tt+1)->buf[(tt+1)&1], issue loads tile tt+2,
// compute tile tt from buf[tt&1], ONE __syncthreads(). Plain per-lane global
// loads (register dest) cross the barrier without a vmcnt drain.
// LDS: 2 stages x (sK 64x72 + sV 64x72) = 36 KB; reused as epilogue scratch.
// ---------------------------------------------------------------------------
__global__ __launch_bounds__(256, 2) void attn_kernel(
    const bf16* __restrict__ qbuf, const bf16* __restrict__ kbuf,
    const bf16* __restrict__ vT, bf16* __restrict__ concat)
{
    __shared__ bf16 sKV[4 * 64 * 72];   // [stage][K|V], 36 KB

    const int tid  = threadIdx.x;
    const int lane = tid & 63;
    const int w    = tid >> 6;
    const int r    = lane & 15;
    const int qd   = lane >> 4;
    const int qt   = blockIdx.x;        // 0..15
    const int bh   = blockIdx.y;        // 0..31
    const int b    = bh >> 4, h = bh & 15;
    const int qrow0 = b * 2048 + qt * 128;
    const size_t vbase = (size_t)bh * 64 * 2048;

    // all-ones A-frag for the row-sum MFMA (bf16 1.0 = 0x3F80)
    const s16x4 ones4 = {(short)0x3F80, (short)0x3F80, (short)0x3F80, (short)0x3F80};

    // staging geometry (fixed per thread)
    int krow[2], kch[2];
#pragma unroll
    for (int t = 0; t < 2; ++t) {
        int flat = t * 256 + tid;        // 0..511
        krow[t] = flat >> 3; kch[t] = flat & 7;
    }

    // Q fragments in registers: rows w*32+mi*16+r, cols ks*32+qd*8 (pre-scaled)
    bf16x8 aq[2][2];
#pragma unroll
    for (int mi = 0; mi < 2; ++mi)
#pragma unroll
        for (int ks = 0; ks < 2; ++ks)
            aq[mi][ks] = *(const bf16x8*)&qbuf[
                (size_t)(qrow0 + w * 32 + mi * 16 + r) * 1024 + h * 64 + ks * 32 + qd * 8];

    f32x4 acc_o[2][4], acc_l[2];        // O^T tiles [mi][pj]; l per mi
    const f32x4 zero4 = {0.f, 0.f, 0.f, 0.f};
#pragma unroll
    for (int mi = 0; mi < 2; ++mi) {
        acc_l[mi] = zero4;
#pragma unroll
        for (int pj = 0; pj < 4; ++pj) acc_o[mi][pj] = zero4;
    }

    bf16x8 rk[2], rv[2];
    // prologue: tile 0 -> buf0; tile 1 -> regs
#pragma unroll
    for (int t = 0; t < 2; ++t) {
        rk[t] = *(const bf16x8*)&kbuf[(size_t)(b * 2048 + krow[t]) * 1024 + h * 64 + kch[t] * 8];
        rv[t] = *(const bf16x8*)&vT[vbase + (size_t)krow[t] * 2048 + kch[t] * 8];
    }
#pragma unroll
    for (int t = 0; t < 2; ++t) {
        *(bf16x8*)&sKV[0 * 4608 + krow[t] * 72 + kch[t] * 8] = rk[t];
        *(bf16x8*)&sKV[1 * 4608 + krow[t] * 72 + kch[t] * 8] = rv[t];
    }
#pragma unroll
    for (int t = 0; t < 2; ++t) {
        rk[t] = *(const bf16x8*)&kbuf[(size_t)(b * 2048 + 64 + krow[t]) * 1024 + h * 64 + kch[t] * 8];
        rv[t] = *(const bf16x8*)&vT[vbase + (size_t)krow[t] * 2048 + 64 + kch[t] * 8];
    }
    __syncthreads();

    for (int tt = 0; tt < 32; ++tt) {
        // store tile tt+1 into the other stage (its readers finished at the
        // last barrier); then issue loads for tile tt+2
        {
            int st = (tt + 1) & 1;
#pragma unroll
            for (int t = 0; t < 2; ++t) {
                *(bf16x8*)&sKV[(2 * st + 0) * 4608 + krow[t] * 72 + kch[t] * 8] = rk[t];
                *(bf16x8*)&sKV[(2 * st + 1) * 4608 + krow[t] * 72 + kch[t] * 8] = rv[t];
            }
        }
        {
            int nxt = (tt + 2 < 32) ? tt + 2 : 31;
#pragma unroll
            for (int t = 0; t < 2; ++t) {
                rk[t] = *(const bf16x8*)&kbuf[(size_t)(b * 2048 + nxt * 64 + krow[t]) * 1024 + h * 64 + kch[t] * 8];
                rv[t] = *(const bf16x8*)&vT[vbase + (size_t)krow[t] * 2048 + nxt * 64 + kch[t] * 8];
            }
        }
        const bf16* sK = &sKV[(2 * (tt & 1) + 0) * 4608];
        const bf16* sV = &sKV[(2 * (tt & 1) + 1) * 4608];

        // S^T = K Q^T : D[t][q], col = lane&15 = q, row t = qd*4 + i
        f32x4 accs[2][4];
#pragma unroll
        for (int mi = 0; mi < 2; ++mi)
#pragma unroll
            for (int ni = 0; ni < 4; ++ni) accs[mi][ni] = zero4;
#pragma unroll
        for (int ks = 0; ks < 2; ++ks)
#pragma unroll
            for (int ni = 0; ni < 4; ++ni) {
                bf16x8 ak = *(const bf16x8*)&sK[(ni * 16 + r) * 72 + ks * 32 + qd * 8];
#pragma unroll
                for (int mi = 0; mi < 2; ++mi)
                    accs[mi][ni] = __builtin_amdgcn_mfma_f32_16x16x32_bf16(
                        ak, aq[mi][ks], accs[mi][ni], 0, 0, 0);
            }

        // P^T = exp2(S^T), packed bf16 -> B-frag of the K=16 MFMA
        s16x4 pfrag[2][4];
#pragma unroll
        for (int mi = 0; mi < 2; ++mi)
#pragma unroll
            for (int ni = 0; ni < 4; ++ni) {
                bf16x4 pv;
#pragma unroll
                for (int i = 0; i < 4; ++i) pv[i] = (bf16)exp2f(accs[mi][ni][i]);
                pfrag[mi][ni] = __builtin_bit_cast(s16x4, pv);
            }

        // O^T += V^T P^T ; l += 1^T P^T   (K=16 MFMAs)
#pragma unroll
        for (int ni = 0; ni < 4; ++ni) {
#pragma unroll
            for (int pj = 0; pj < 4; ++pj) {
                bf16x4 av = *(const bf16x4*)&sV[(pj * 16 + r) * 72 + ni * 16 + qd * 4];
                s16x4  avs = __builtin_bit_cast(s16x4, av);
#pragma unroll
                for (int mi = 0; mi < 2; ++mi)
                    acc_o[mi][pj] = __builtin_amdgcn_mfma_f32_16x16x16bf16_1k(
                        avs, pfrag[mi][ni], acc_o[mi][pj], 0, 0, 0);
            }
#pragma unroll
            for (int mi = 0; mi < 2; ++mi)
                acc_l[mi] = __builtin_amdgcn_mfma_f32_16x16x16bf16_1k(
                    ones4, pfrag[mi][ni], acc_l[mi], 0, 0, 0);
        }

        __syncthreads();   // single barrier per iteration
    }

    // epilogue: O^T -> O via LDS scratch (stride 72: conflict-free writes),
    // then coalesced b128 stores. l for column q = acc_l[mi][0].
    bf16* scratch = sKV;                 // 128 x 72 (18 KB of the 36)
#pragma unroll
    for (int mi = 0; mi < 2; ++mi) {
        float inv = 1.0f / acc_l[mi][0];
        int qloc  = w * 32 + mi * 16 + r;
#pragma unroll
        for (int pj = 0; pj < 4; ++pj)
#pragma unroll
            for (int i = 0; i < 4; ++i)
                scratch[qloc * 72 + pj * 16 + qd * 4 + i] =
                    (bf16)(acc_o[mi][pj][i] * inv);
    }
    __syncthreads();
    {
        int row  = tid >> 1;             // 0..127
        int half = tid & 1;              // 32-elem half-row
#pragma unroll
        for (int c = 0; c < 4; ++c) {
            bf16x8 v = *(const bf16x8*)&scratch[row * 72 + half * 32 + c * 8];
            *(bf16x8*)&concat[(size_t)(qrow0 + row) * 1024 + h * 64 + half * 32 + c * 8] = v;
        }
    }
}

// ---------------------------------------------------------------------------
extern "C" void kernel_launch(void* const* d_in, const int* in_sizes, int n_in,
                              void* d_out, int out_size, void* d_ws, size_t ws_size,
                              hipStream_t stream)
{
    const float* x  = (const float*)d_in[0];   // [4096, 1024]
    const float* Wq = (const float*)d_in[1];
    const float* Wk = (const float*)d_in[2];
    const float* Wv = (const float*)d_in[3];
    const float* Wo = (const float*)d_in[4];
    const float* bo = (const float*)d_in[5];
    float* out = (float*)d_out;

    char* ws = (char*)d_ws;
    bf16* xb     = (bf16*)(ws);
    bf16* Wqb    = (bf16*)(ws + (8u  << 20));
    bf16* Wkb    = (bf16*)(ws + (10u << 20));
    bf16* Wvb    = (bf16*)(ws + (12u << 20));
    bf16* Wob    = (bf16*)(ws + (14u << 20));
    bf16* qbuf   = (bf16*)(ws + (16u << 20)); // pre-scaled by QSCALE
    bf16* kbuf   = (bf16*)(ws + (24u << 20));
    bf16* vT     = (bf16*)(ws + (32u << 20)); // [32][64][2048]
    bf16* concat = (bf16*)(ws + (40u << 20));

    hipLaunchKernelGGL(cvt_f32_bf16, dim3(2048, 5), dim3(256), 0, stream,
                       x, Wq, Wk, Wv, Wo, xb, Wqb, Wkb, Wvb, Wob);
    hipLaunchKernelGGL(qkv_gemm, dim3(24, 32), dim3(256), 0, stream,
                       xb, Wqb, Wkb, Wvb, qbuf, kbuf, vT);
    hipLaunchKernelGGL(attn_kernel, dim3(16, 32), dim3(256), 0, stream,
                       qbuf, kbuf, vT, concat);
    hipLaunchKernelGGL(out_gemm, dim3(16, 32), dim3(256), 0, stream,
                       concat, Wob, out, bo);
}